// Round 1
// baseline (564.822 us; speedup 1.0000x reference)
//
#include <hip/hip_runtime.h>

// MultiHeadAttention (B=2, L=2048, C=256, H=W=4, NH=8, DH=32)
// Pipeline: prep(transpose+bf16) -> proj GEMMs -> score GEMM -> softmax -> V-transpose -> context GEMM
// All GEMMs: bf16 MFMA 16x16x32, fp32 accum, 128x128 tile, 4 waves.
//
// Workspace layout (shorts):
//   X    @ 0          : 16,777,216  (reused per-projection input; later aliased as v_t)
//   q_s  @ 16,777,216 : 16,777,216  [bh][l][512]
//   k_s  @ 33,554,432 : 16,777,216
//   v_s  @ 50,331,648 : 16,777,216
//   Wbf  @ 67,108,864 : 196,608     (Wq,Wk,Wv bf16)
// Total = 134,610,944 bytes required of d_ws.

typedef short s16x8 __attribute__((ext_vector_type(8)));
typedef float f32x4 __attribute__((ext_vector_type(4)));

__device__ __forceinline__ unsigned short f2bf(float f) {
  union { float f; unsigned int u; } v; v.f = f;
  return (unsigned short)((v.u + 0x7FFFu + ((v.u >> 16) & 1u)) >> 16);  // RNE
}

// ---------------- prep: (B,L,C,H,W) fp32 -> X[(b,l,hw)][c] bf16 ----------------
__global__ void __launch_bounds__(256) prep_x_kernel(const float* __restrict__ src,
                                                     unsigned short* __restrict__ dst) {
  __shared__ float ld[256 * 17];
  const int bl = blockIdx.x;   // b*2048 + l
  const int t = threadIdx.x;
  const float* s = src + (size_t)bl * 4096;
#pragma unroll
  for (int i = 0; i < 4; ++i) {
    int flat = i * 1024 + t * 4;          // (c,hw) linear
    float4 v = *(const float4*)(s + flat);
    int c = flat >> 4, hw = flat & 15;
    float* p = &ld[c * 17 + hw];
    p[0] = v.x; p[1] = v.y; p[2] = v.z; p[3] = v.w;
  }
  __syncthreads();
  unsigned short* d = dst + (size_t)bl * 4096;  // X[(bl*16+hw)*256 + c]
#pragma unroll
  for (int hw = 0; hw < 16; ++hw)
    d[hw * 256 + t] = f2bf(ld[t * 17 + hw]);
}

__global__ void __launch_bounds__(256) prep_w_kernel(const float* __restrict__ a,
                                                     const float* __restrict__ b,
                                                     const float* __restrict__ c,
                                                     unsigned short* __restrict__ dst) {
  int i = blockIdx.x * 256 + threadIdx.x;  // < 196608
  const float* s = (i < 65536) ? a : ((i < 131072) ? b : c);
  dst[i] = f2bf(s[i & 65535]);
}

// ---------------- shared GEMM core: C(128x128) += A(128xK) * Bt(128xK)^T ----------------
// A row-major (M,K) k-contiguous; Bt row-major (N,K) k-contiguous. bf16.
__device__ __forceinline__ void gemm_core_bf16(const unsigned short* __restrict__ Ag, int ldA,
                                               const unsigned short* __restrict__ Bg, int ldB,
                                               int K, unsigned short* As, unsigned short* Bs,
                                               f32x4 acc[4][4]) {
  const int tid = threadIdx.x;
  const int lane = tid & 63;
  const int w = tid >> 6;
  const int wr = (w >> 1) * 64, wc = (w & 1) * 64;
  for (int k0 = 0; k0 < K; k0 += 32) {
#pragma unroll
    for (int s = 0; s < 2; ++s) {
      int flat = (s * 256 + tid) * 8;     // element index in [128][32] tile
      int row = flat >> 5, kk = flat & 31;
      *(s16x8*)(As + flat) = *(const s16x8*)(Ag + (size_t)row * ldA + k0 + kk);
      *(s16x8*)(Bs + flat) = *(const s16x8*)(Bg + (size_t)row * ldB + k0 + kk);
    }
    __syncthreads();
    s16x8 af[4], bfv[4];
#pragma unroll
    for (int m = 0; m < 4; ++m)
      af[m] = *(const s16x8*)(As + (wr + m * 16 + (lane & 15)) * 32 + (lane >> 4) * 8);
#pragma unroll
    for (int n = 0; n < 4; ++n)
      bfv[n] = *(const s16x8*)(Bs + (wc + n * 16 + (lane & 15)) * 32 + (lane >> 4) * 8);
#pragma unroll
    for (int m = 0; m < 4; ++m)
#pragma unroll
      for (int n = 0; n < 4; ++n)
        acc[m][n] = __builtin_amdgcn_mfma_f32_16x16x32_bf16(af[m], bfv[n], acc[m][n], 0, 0, 0);
    __syncthreads();
  }
}

#define ACC_INIT(acc)                         \
  {                                           \
    const f32x4 z_ = {0.f, 0.f, 0.f, 0.f};    \
    _Pragma("unroll")                         \
    for (int m_ = 0; m_ < 4; ++m_)            \
      _Pragma("unroll")                       \
      for (int n_ = 0; n_ < 4; ++n_) acc[m_][n_] = z_; \
  }

// ---------------- projection: X(65536x256) * W(256x256)^T -> q_s[bh][l][512] bf16 ----------------
__global__ void __launch_bounds__(256) gemm_proj_kernel(const unsigned short* __restrict__ X,
                                                        const unsigned short* __restrict__ W,
                                                        unsigned short* __restrict__ out) {
  __shared__ unsigned short As[4096], Bs[4096];
  f32x4 acc[4][4];
  ACC_INIT(acc);
  gemm_core_bf16(X + (size_t)blockIdx.x * 128 * 256, 256,
                 W + (size_t)blockIdx.y * 128 * 256, 256, 256, As, Bs, acc);
  const int tid = threadIdx.x, lane = tid & 63, w = tid >> 6;
  const int wr = (w >> 1) * 64, wc = (w & 1) * 64;
  const int R0 = blockIdx.x * 128 + wr + ((lane >> 4) << 2);
  const int C0 = blockIdx.y * 128 + wc + (lane & 15);
#pragma unroll
  for (int m = 0; m < 4; ++m)
#pragma unroll
    for (int n = 0; n < 4; ++n)
#pragma unroll
      for (int r = 0; r < 4; ++r) {
        int R = R0 + m * 16 + r;          // position p = (b*L + l)*16 + hw
        int o = C0 + n * 16;              // output channel
        int bl = R >> 4, hw = R & 15;
        int b = bl >> 11, l = bl & 2047;
        int head = o >> 5, d = o & 31;
        out[((size_t)(head * 2 + b) * 2048 + l) * 512 + d * 16 + hw] = f2bf(acc[m][n][r]);
      }
}

// ---------------- score: q_s[bh] (2048x512) * k_s[bh]^T -> attn (raw, scaled) fp32 ----------------
__global__ void __launch_bounds__(256) gemm_score_kernel(const unsigned short* __restrict__ q,
                                                         const unsigned short* __restrict__ k,
                                                         float* __restrict__ attn) {
  __shared__ unsigned short As[4096], Bs[4096];
  f32x4 acc[4][4];
  ACC_INIT(acc);
  const int bh = blockIdx.z;
  gemm_core_bf16(q + ((size_t)bh * 2048 + blockIdx.x * 128) * 512, 512,
                 k + ((size_t)bh * 2048 + blockIdx.y * 128) * 512, 512, 512, As, Bs, acc);
  const int tid = threadIdx.x, lane = tid & 63, w = tid >> 6;
  const int wr = (w >> 1) * 64, wc = (w & 1) * 64;
  float* O = attn + (size_t)bh * 2048 * 2048;
  const float scale = 0.17677669529663687f;  // 1/sqrt(32)
  const int R0 = blockIdx.x * 128 + wr + ((lane >> 4) << 2);
  const int C0 = blockIdx.y * 128 + wc + (lane & 15);
#pragma unroll
  for (int m = 0; m < 4; ++m)
#pragma unroll
    for (int n = 0; n < 4; ++n)
#pragma unroll
      for (int r = 0; r < 4; ++r)
        O[(size_t)(R0 + m * 16 + r) * 2048 + (C0 + n * 16)] = acc[m][n][r] * scale;
}

// ---------------- softmax over rows of attn (in place) ----------------
__global__ void __launch_bounds__(256) softmax_kernel(float* __restrict__ attn) {
  __shared__ float red[4];
  float* p = attn + (size_t)blockIdx.x * 2048;
  const int t = threadIdx.x;
  float4 v0 = *(const float4*)(p + t * 8);
  float4 v1 = *(const float4*)(p + t * 8 + 4);
  float mx = fmaxf(fmaxf(fmaxf(v0.x, v0.y), fmaxf(v0.z, v0.w)),
                   fmaxf(fmaxf(v1.x, v1.y), fmaxf(v1.z, v1.w)));
#pragma unroll
  for (int off = 32; off; off >>= 1) mx = fmaxf(mx, __shfl_xor(mx, off));
  if ((t & 63) == 0) red[t >> 6] = mx;
  __syncthreads();
  mx = fmaxf(fmaxf(red[0], red[1]), fmaxf(red[2], red[3]));
  __syncthreads();  // before red[] reuse
  float e[8];
  e[0] = __expf(v0.x - mx); e[1] = __expf(v0.y - mx);
  e[2] = __expf(v0.z - mx); e[3] = __expf(v0.w - mx);
  e[4] = __expf(v1.x - mx); e[5] = __expf(v1.y - mx);
  e[6] = __expf(v1.z - mx); e[7] = __expf(v1.w - mx);
  float s = ((e[0] + e[1]) + (e[2] + e[3])) + ((e[4] + e[5]) + (e[6] + e[7]));
#pragma unroll
  for (int off = 32; off; off >>= 1) s += __shfl_xor(s, off);
  if ((t & 63) == 0) red[t >> 6] = s;
  __syncthreads();
  s = red[0] + red[1] + red[2] + red[3];
  const float inv = 1.0f / s;
  float4 o0 = {e[0] * inv, e[1] * inv, e[2] * inv, e[3] * inv};
  float4 o1 = {e[4] * inv, e[5] * inv, e[6] * inv, e[7] * inv};
  *(float4*)(p + t * 8) = o0;
  *(float4*)(p + t * 8 + 4) = o1;
}

// ---------------- v_s[bh][j][dd] -> v_t[bh][dd][j] (bf16 transpose) ----------------
__global__ void __launch_bounds__(256) transpose_v_kernel(const unsigned short* __restrict__ vs,
                                                          unsigned short* __restrict__ vt) {
  __shared__ unsigned short tile[64][65];
  const int bh = blockIdx.z;
  const int j0 = blockIdx.x * 64, d0 = blockIdx.y * 64;
  const unsigned short* src = vs + (size_t)bh * 2048 * 512;
  unsigned short* dst = vt + (size_t)bh * 512 * 2048;
  const int t = threadIdx.x;
#pragma unroll
  for (int i = 0; i < 16; ++i) {
    int e = t * 16 + i;
    int r = e >> 6, c = e & 63;          // r = j idx, c = dd idx
    tile[r][c] = src[(size_t)(j0 + r) * 512 + d0 + c];
  }
  __syncthreads();
#pragma unroll
  for (int i = 0; i < 16; ++i) {
    int e = t * 16 + i;
    int r = e >> 6, c = e & 63;          // r = dd idx, c = j idx
    dst[(size_t)(d0 + r) * 2048 + j0 + c] = tile[c][r];
  }
}

// ---------------- context: attn(fp32, 2048x2048) * v_t^T -> out (B,L,C,H,W) fp32 ----------------
__global__ void __launch_bounds__(256) gemm_ctx_kernel(const float* __restrict__ attn,
                                                       const unsigned short* __restrict__ vt,
                                                       float* __restrict__ outc) {
  __shared__ unsigned short As[4096], Bs[4096];
  f32x4 acc[4][4];
  ACC_INIT(acc);
  const int tid = threadIdx.x, lane = tid & 63, w = tid >> 6;
  const int wr = (w >> 1) * 64, wc = (w & 1) * 64;
  const int bh = blockIdx.z;
  const float* Ag = attn + (size_t)bh * 2048 * 2048 + (size_t)blockIdx.x * 128 * 2048;
  const unsigned short* Bg = vt + (size_t)bh * 512 * 2048 + (size_t)blockIdx.y * 128 * 2048;
  const int arow = tid >> 1, akk = (tid & 1) * 16;
  for (int k0 = 0; k0 < 2048; k0 += 32) {
    {  // A stage: fp32 -> bf16, tile [128][32]
      const float* sp = Ag + (size_t)arow * 2048 + k0 + akk;
      float4 f0 = *(const float4*)(sp);
      float4 f1 = *(const float4*)(sp + 4);
      float4 f2 = *(const float4*)(sp + 8);
      float4 f3 = *(const float4*)(sp + 12);
      s16x8 h0, h1;
      h0[0] = (short)f2bf(f0.x); h0[1] = (short)f2bf(f0.y);
      h0[2] = (short)f2bf(f0.z); h0[3] = (short)f2bf(f0.w);
      h0[4] = (short)f2bf(f1.x); h0[5] = (short)f2bf(f1.y);
      h0[6] = (short)f2bf(f1.z); h0[7] = (short)f2bf(f1.w);
      h1[0] = (short)f2bf(f2.x); h1[1] = (short)f2bf(f2.y);
      h1[2] = (short)f2bf(f2.z); h1[3] = (short)f2bf(f2.w);
      h1[4] = (short)f2bf(f3.x); h1[5] = (short)f2bf(f3.y);
      h1[6] = (short)f2bf(f3.z); h1[7] = (short)f2bf(f3.w);
      *(s16x8*)(As + arow * 32 + akk) = h0;
      *(s16x8*)(As + arow * 32 + akk + 8) = h1;
    }
#pragma unroll
    for (int s = 0; s < 2; ++s) {  // B stage (bf16 direct)
      int flat = (s * 256 + tid) * 8;
      int row = flat >> 5, kk = flat & 31;
      *(s16x8*)(Bs + flat) = *(const s16x8*)(Bg + (size_t)row * 2048 + k0 + kk);
    }
    __syncthreads();
    s16x8 af[4], bfv[4];
#pragma unroll
    for (int m = 0; m < 4; ++m)
      af[m] = *(const s16x8*)(As + (wr + m * 16 + (lane & 15)) * 32 + (lane >> 4) * 8);
#pragma unroll
    for (int n = 0; n < 4; ++n)
      bfv[n] = *(const s16x8*)(Bs + (wc + n * 16 + (lane & 15)) * 32 + (lane >> 4) * 8);
#pragma unroll
    for (int m = 0; m < 4; ++m)
#pragma unroll
      for (int n = 0; n < 4; ++n)
        acc[m][n] = __builtin_amdgcn_mfma_f32_16x16x32_bf16(af[m], bfv[n], acc[m][n], 0, 0, 0);
    __syncthreads();
  }
  const int b = bh & 1, head = bh >> 1;
  const int R0 = blockIdx.x * 128 + wr + ((lane >> 4) << 2);
  const int C0 = blockIdx.y * 128 + wc + (lane & 15);
#pragma unroll
  for (int m = 0; m < 4; ++m)
#pragma unroll
    for (int n = 0; n < 4; ++n)
#pragma unroll
      for (int r = 0; r < 4; ++r) {
        int R = R0 + m * 16 + r;         // sequence position i
        int dd = C0 + n * 16;            // d*16 + hw
        int d = dd >> 4, hw = dd & 15;
        outc[((size_t)(b * 2048 + R) * 256 + head * 32 + d) * 16 + hw] = acc[m][n][r];
      }
}

extern "C" void kernel_launch(void* const* d_in, const int* in_sizes, int n_in,
                              void* d_out, int out_size, void* d_ws, size_t ws_size,
                              hipStream_t stream) {
  const float* query = (const float*)d_in[0];
  const float* key   = (const float*)d_in[1];
  const float* value = (const float*)d_in[2];
  const float* Wq    = (const float*)d_in[3];
  const float* Wk    = (const float*)d_in[4];
  const float* Wv    = (const float*)d_in[5];

  float* out_ctx  = (float*)d_out;                   // 16,777,216 fp32
  float* out_attn = (float*)d_out + 16777216;        // 67,108,864 fp32

  unsigned short* X   = (unsigned short*)d_ws;       // reused input buffer / later v_t
  unsigned short* q_s = X + 16777216;
  unsigned short* k_s = q_s + 16777216;
  unsigned short* v_s = k_s + 16777216;
  unsigned short* Wbf = v_s + 16777216;              // 3 * 65536
  unsigned short* v_t = X;                           // alias (X dead after proj v)

  prep_w_kernel<<<768, 256, 0, stream>>>(Wq, Wk, Wv, Wbf);

  prep_x_kernel<<<4096, 256, 0, stream>>>(query, X);
  gemm_proj_kernel<<<dim3(512, 2), 256, 0, stream>>>(X, Wbf, q_s);

  prep_x_kernel<<<4096, 256, 0, stream>>>(key, X);
  gemm_proj_kernel<<<dim3(512, 2), 256, 0, stream>>>(X, Wbf + 65536, k_s);

  prep_x_kernel<<<4096, 256, 0, stream>>>(value, X);
  gemm_proj_kernel<<<dim3(512, 2), 256, 0, stream>>>(X, Wbf + 131072, v_s);

  gemm_score_kernel<<<dim3(16, 16, 16), 256, 0, stream>>>(q_s, k_s, out_attn);
  softmax_kernel<<<32768, 256, 0, stream>>>(out_attn);
  transpose_v_kernel<<<dim3(32, 8, 16), 256, 0, stream>>>(v_s, v_t);
  gemm_ctx_kernel<<<dim3(16, 4, 16), 256, 0, stream>>>(out_attn, v_t, out_ctx);
}